// Round 1
// baseline (637.484 us; speedup 1.0000x reference)
//
#include <hip/hip_runtime.h>
#include <hip/hip_bf16.h>
#include <math.h>

// B=2 QL=512 KL=8192 D=1024 H=8 HD=128
typedef __attribute__((ext_vector_type(4))) float fx4;
typedef __attribute__((ext_vector_type(4))) short sx4;
typedef __attribute__((ext_vector_type(8))) short sx8;

#define MFMA16(a, b, c) __builtin_amdgcn_mfma_f32_16x16x16bf16_1k(a, b, c, 0, 0, 0)

__device__ __forceinline__ unsigned short f2bf(float f) {
  unsigned int u = __float_as_uint(f);
  return (unsigned short)((u + 0x7fffu + ((u >> 16) & 1u)) >> 16);  // RNE
}

// ---------------- mask pack: int32 [2,512,8192] -> u64 bitmask [2,512,128] ----
__global__ __launch_bounds__(256) void k_pack_mask(const int* __restrict__ mask,
                                                   unsigned long long* __restrict__ mb) {
  int g = blockIdx.x * 256 + threadIdx.x;
  unsigned long long bal = __ballot(mask[g] != 0);
  if ((threadIdx.x & 63) == 0) mb[g >> 6] = bal;
}

// ---------------- GEMM: C[M,N] = A[M,K] @ B[N,K]^T + bias --------------------
// A: f32 (cast to bf16 in staging) or bf16. B: f32 weights. C: bf16 or f32.
// 128x128 tile, BK=32, 256 threads (4 waves, 2x2), legacy 16x16x16 bf16 MFMA.
template <bool A_IS_F32, bool OUT_IS_F32>
__global__ __launch_bounds__(256) void k_gemm_bt(const void* __restrict__ Aptr,
                                                 const float* __restrict__ Bw,
                                                 const float* __restrict__ bias,
                                                 void* __restrict__ Cptr,
                                                 int M, int N, int K) {
  __shared__ __align__(16) short sA[128 * 40];  // +8 pad: 2-way banks only
  __shared__ __align__(16) short sB[128 * 40];
  const int t = threadIdx.x;
  const int lane = t & 63;
  const int w = t >> 6;
  const int quad = lane >> 4;
  const int l16 = lane & 15;
  const int mt = M >> 7;
  const int m0 = (blockIdx.x % mt) << 7;
  const int n0 = (blockIdx.x / mt) << 7;
  const int wm = (w >> 1) << 6;
  const int wn = (w & 1) << 6;
  const fx4 fzero = {0.f, 0.f, 0.f, 0.f};
  fx4 acc[4][4];
#pragma unroll
  for (int i = 0; i < 4; i++)
#pragma unroll
    for (int j = 0; j < 4; j++) acc[i][j] = fzero;

  for (int k0 = 0; k0 < K; k0 += 32) {
    __syncthreads();
    if (A_IS_F32) {
      const float* A = (const float*)Aptr;
      const int kk = (t & 7) * 4;
#pragma unroll
      for (int j = 0; j < 4; j++) {
        const int r = (t >> 3) + j * 32;
        const fx4 v = *(const fx4*)(A + (size_t)(m0 + r) * K + k0 + kk);
        sx4 pk;
        pk[0] = (short)f2bf(v[0]); pk[1] = (short)f2bf(v[1]);
        pk[2] = (short)f2bf(v[2]); pk[3] = (short)f2bf(v[3]);
        *(sx4*)(&sA[r * 40 + kk]) = pk;
      }
    } else {
      const short* A = (const short*)Aptr;
      const int kk = (t & 3) * 8;
#pragma unroll
      for (int j = 0; j < 2; j++) {
        const int r = (t >> 2) + j * 64;
        *(sx8*)(&sA[r * 40 + kk]) = *(const sx8*)(A + (size_t)(m0 + r) * K + k0 + kk);
      }
    }
    {
      const int kk = (t & 7) * 4;
#pragma unroll
      for (int j = 0; j < 4; j++) {
        const int r = (t >> 3) + j * 32;
        const fx4 v = *(const fx4*)(Bw + (size_t)(n0 + r) * K + k0 + kk);
        sx4 pk;
        pk[0] = (short)f2bf(v[0]); pk[1] = (short)f2bf(v[1]);
        pk[2] = (short)f2bf(v[2]); pk[3] = (short)f2bf(v[3]);
        *(sx4*)(&sB[r * 40 + kk]) = pk;
      }
    }
    __syncthreads();
    sx4 fa[4][2], fb[4][2];
#pragma unroll
    for (int i = 0; i < 4; i++)
#pragma unroll
      for (int kc = 0; kc < 2; kc++) {
        fa[i][kc] = *(const sx4*)(&sA[(wm + i * 16 + l16) * 40 + kc * 16 + quad * 4]);
        fb[i][kc] = *(const sx4*)(&sB[(wn + i * 16 + l16) * 40 + kc * 16 + quad * 4]);
      }
#pragma unroll
    for (int kc = 0; kc < 2; kc++)
#pragma unroll
      for (int mi = 0; mi < 4; mi++)
#pragma unroll
        for (int ni = 0; ni < 4; ni++)
          acc[mi][ni] = MFMA16(fa[mi][kc], fb[ni][kc], acc[mi][ni]);
  }
  // epilogue: C/D layout col=lane&15, row=quad*4+reg (absolute within 16x16)
#pragma unroll
  for (int ni = 0; ni < 4; ni++) {
    const int col = n0 + wn + ni * 16 + l16;
    const float bval = bias[col];
#pragma unroll
    for (int mi = 0; mi < 4; mi++)
#pragma unroll
      for (int r = 0; r < 4; r++) {
        const int row = m0 + wm + mi * 16 + quad * 4 + r;
        const float v = acc[mi][ni][r] + bval;
        if (OUT_IS_F32) ((float*)Cptr)[(size_t)row * N + col] = v;
        else ((unsigned short*)Cptr)[(size_t)row * N + col] = f2bf(v);
      }
  }
}

// ---------------- V transpose: Vp[16384,1024]bf16 -> Vt[2][1024][8192] -------
__global__ __launch_bounds__(256) void k_transpose_v(const short* __restrict__ Vp,
                                                     short* __restrict__ Vt) {
  __shared__ __align__(16) short tile[64 * 72];
  const int x = blockIdx.x;
  const int tm = x & 255;   // kl tile (16384/64)
  const int td = x >> 8;    // d tile (1024/64)
  const int m0 = tm << 6;
  const int b = m0 >> 13;
  const int kl0 = m0 & 8191;
  const int d0 = td << 6;
  const int t = threadIdx.x;
  const int c = t & 7;
#pragma unroll
  for (int j = 0; j < 2; j++) {
    const int r = (t >> 3) + j * 32;
    *(sx8*)(&tile[r * 72 + c * 8]) = *(const sx8*)(Vp + (size_t)(m0 + r) * 1024 + d0 + c * 8);
  }
  __syncthreads();
#pragma unroll
  for (int j = 0; j < 2; j++) {
    const int d = (t >> 3) + j * 32;
    sx8 v;
#pragma unroll
    for (int i = 0; i < 8; i++) v[i] = tile[(c * 8 + i) * 72 + d];
    *(sx8*)(Vt + (size_t)(b * 1024 + d0 + d) * 8192 + kl0 + c * 8) = v;
  }
}

// ---------------- flash attention partials -----------------------------------
// grid 512: x = s + 4*(qt + 8*(h + 8*b)); WG: 64 q rows, 2048-key chunk.
// Each wave owns 16 q rows (full key range): online softmax state wave-local.
__global__ __launch_bounds__(256) void k_attn(const short* __restrict__ Qp,
                                              const short* __restrict__ Kp,
                                              const short* __restrict__ Vt,
                                              const unsigned long long* __restrict__ mb,
                                              float* __restrict__ ml,
                                              float* __restrict__ Op) {
  __shared__ __align__(16) short sQ[64 * 136];
  __shared__ __align__(16) short sK[64 * 136];
  __shared__ __align__(16) short sV[128 * 72];
  __shared__ __align__(16) short sP[4 * 16 * 72];
  const int x = blockIdx.x;
  const int s = x & 3;
  const int qt = (x >> 2) & 7;
  const int h = (x >> 5) & 7;
  const int b = x >> 8;
  const int t = threadIdx.x;
  const int lane = t & 63;
  const int w = t >> 6;
  const int quad = lane >> 4;
  const int l16 = lane & 15;
  const int q0 = qt << 6;
  const fx4 fzero = {0.f, 0.f, 0.f, 0.f};
  {
    const int c = t & 15;
#pragma unroll
    for (int j = 0; j < 4; j++) {
      const int r = (t >> 4) + j * 16;
      *(sx8*)(&sQ[r * 136 + c * 8]) =
          *(const sx8*)(Qp + (size_t)(b * 512 + q0 + r) * 1024 + h * 128 + c * 8);
    }
  }
  __syncthreads();
  sx4 aq[8];  // Q A-frags for this wave's 16 rows, whole HD=128
#pragma unroll
  for (int kc = 0; kc < 8; kc++)
    aq[kc] = *(const sx4*)(&sQ[(w * 16 + l16) * 136 + kc * 16 + quad * 4]);
  float m[4], l[4];
#pragma unroll
  for (int r = 0; r < 4; r++) { m[r] = -INFINITY; l[r] = 0.f; }
  fx4 O[8];
#pragma unroll
  for (int d = 0; d < 8; d++) O[d] = fzero;
  const float scale = 0.08838834764831845f;  // 1/sqrt(128)
  const int key_base = s * 2048;

  for (int kt = 0; kt < 32; kt++) {
    const int key0 = key_base + kt * 64;
    __syncthreads();
    {  // stage K tile [64 keys][128]
      const int c = t & 15;
#pragma unroll
      for (int j = 0; j < 4; j++) {
        const int r = (t >> 4) + j * 16;
        *(sx8*)(&sK[r * 136 + c * 8]) =
            *(const sx8*)(Kp + (size_t)(b * 8192 + key0 + r) * 1024 + h * 128 + c * 8);
      }
    }
    {  // stage V^T tile [128 d][64 keys]
      const int c8 = t & 7;
#pragma unroll
      for (int j = 0; j < 4; j++) {
        const int d = (t >> 3) + j * 32;
        *(sx8*)(&sV[d * 72 + c8 * 8]) =
            *(const sx8*)(Vt + (size_t)(b * 1024 + h * 128 + d) * 8192 + key0 + c8 * 8);
      }
    }
    __syncthreads();
    // QK^T: S[16 q][64 keys] per wave
    fx4 sc[4];
#pragma unroll
    for (int nt = 0; nt < 4; nt++) {
      fx4 a = fzero;
#pragma unroll
      for (int kc = 0; kc < 8; kc++) {
        const sx4 bk = *(const sx4*)(&sK[(nt * 16 + l16) * 136 + kc * 16 + quad * 4]);
        a = MFMA16(aq[kc], bk, a);
      }
      sc[nt] = a;
    }
    unsigned long long wd[4];
#pragma unroll
    for (int r = 0; r < 4; r++)
      wd[r] = mb[(size_t)(b * 512 + q0 + w * 16 + quad * 4 + r) * 128 + (key0 >> 6)];
    float p[4][4], alpha[4];
#pragma unroll
    for (int r = 0; r < 4; r++) {
      float sv[4];
      float mx = -INFINITY;
#pragma unroll
      for (int nt = 0; nt < 4; nt++) {
        float v = sc[nt][r] * scale;
        v = ((wd[r] >> (nt * 16 + l16)) & 1ULL) ? v : -INFINITY;
        sv[nt] = v;
        mx = fmaxf(mx, v);
      }
#pragma unroll
      for (int dd = 1; dd < 16; dd <<= 1) mx = fmaxf(mx, __shfl_xor(mx, dd, 64));
      const float mn = fmaxf(m[r], mx);
      alpha[r] = (m[r] == mn) ? 1.f : __expf(m[r] - mn);  // guards -inf - -inf
      float ps = 0.f;
#pragma unroll
      for (int nt = 0; nt < 4; nt++) {
        const float pv = (sv[nt] <= -1e30f) ? 0.f : __expf(sv[nt] - mn);
        p[nt][r] = pv;
        ps += pv;
      }
#pragma unroll
      for (int dd = 1; dd < 16; dd <<= 1) ps += __shfl_xor(ps, dd, 64);
      l[r] = l[r] * alpha[r] + ps;
      m[r] = mn;
    }
    // P: C/D layout -> LDS -> A layout (wave-private region, no barrier needed)
#pragma unroll
    for (int nt = 0; nt < 4; nt++)
#pragma unroll
      for (int r = 0; r < 4; r++)
        sP[w * 1152 + (quad * 4 + r) * 72 + nt * 16 + l16] = (short)f2bf(p[nt][r]);
#pragma unroll
    for (int dt = 0; dt < 8; dt++)
#pragma unroll
      for (int r = 0; r < 4; r++) O[dt][r] *= alpha[r];
    sx4 pf[4];
#pragma unroll
    for (int kc = 0; kc < 4; kc++)
      pf[kc] = *(const sx4*)(&sP[w * 1152 + l16 * 72 + kc * 16 + quad * 4]);
#pragma unroll
    for (int dt = 0; dt < 8; dt++) {
      fx4 o = O[dt];
#pragma unroll
      for (int kc = 0; kc < 4; kc++) {
        const sx4 vf = *(const sx4*)(&sV[(dt * 16 + l16) * 72 + kc * 16 + quad * 4]);
        o = MFMA16(pf[kc], vf, o);
      }
      O[dt] = o;
    }
  }
  if (l16 == 0) {
#pragma unroll
    for (int r = 0; r < 4; r++) {
      const int row = w * 16 + quad * 4 + r;
      ml[(size_t)x * 128 + row] = m[r];
      ml[(size_t)x * 128 + 64 + row] = l[r];
    }
  }
#pragma unroll
  for (int dt = 0; dt < 8; dt++)
#pragma unroll
    for (int r = 0; r < 4; r++) {
      const int row = w * 16 + quad * 4 + r;
      Op[(size_t)x * 8192 + row * 128 + dt * 16 + l16] = O[dt][r];
    }
}

// ---------------- combine 4 KL-split partials -> summed bf16 -----------------
__global__ __launch_bounds__(256) void k_combine(const float* __restrict__ ml,
                                                 const float* __restrict__ Op,
                                                 short* __restrict__ summed) {
  const int xc = blockIdx.x;  // qt + 8*h + 64*b
  const int qt = xc & 7;
  const int h = (xc >> 3) & 7;
  const int b = xc >> 6;
  const int t = threadIdx.x;
  const int row = t >> 2;
  const int dg = (t & 3) * 32;
  float ms[4], ls[4];
#pragma unroll
  for (int s = 0; s < 4; s++) {
    ms[s] = ml[(size_t)(xc * 4 + s) * 128 + row];
    ls[s] = ml[(size_t)(xc * 4 + s) * 128 + 64 + row];
  }
  const float M = fmaxf(fmaxf(ms[0], ms[1]), fmaxf(ms[2], ms[3]));
  float o[32];
#pragma unroll
  for (int i = 0; i < 32; i++) o[i] = 0.f;
  if (M > -1e30f) {  // else: all-masked row -> wipe to zero
    float L = 0.f, rs[4];
#pragma unroll
    for (int s = 0; s < 4; s++) {
      const float e = __expf(ms[s] - M);
      rs[s] = e;
      L += ls[s] * e;
    }
    const float invL = 1.f / L;  // L >= 1 when M finite
#pragma unroll
    for (int s = 0; s < 4; s++) {
      const float f = rs[s] * invL;
      const float* src = Op + (size_t)(xc * 4 + s) * 8192 + row * 128 + dg;
#pragma unroll
      for (int i = 0; i < 8; i++) {
        const fx4 v = *(const fx4*)(src + i * 4);
        o[i * 4 + 0] += f * v[0];
        o[i * 4 + 1] += f * v[1];
        o[i * 4 + 2] += f * v[2];
        o[i * 4 + 3] += f * v[3];
      }
    }
  }
  short* dst = summed + (size_t)(b * 512 + qt * 64 + row) * 1024 + h * 128 + dg;
#pragma unroll
  for (int i = 0; i < 4; i++) {
    sx8 pk;
#pragma unroll
    for (int j = 0; j < 8; j++) pk[j] = (short)f2bf(o[i * 8 + j]);
    *(sx8*)(dst + i * 8) = pk;
  }
}

// ---------------- host ------------------------------------------------------
extern "C" void kernel_launch(void* const* d_in, const int* in_sizes, int n_in,
                              void* d_out, int out_size, void* d_ws, size_t ws_size,
                              hipStream_t stream) {
  (void)in_sizes; (void)n_in; (void)out_size; (void)ws_size;
  const float* inq = (const float*)d_in[0];
  const float* ink = (const float*)d_in[1];
  const float* inv = (const float*)d_in[2];
  const int* mask = (const int*)d_in[3];
  const float* Wq = (const float*)d_in[4];
  const float* bq = (const float*)d_in[5];
  const float* Wk = (const float*)d_in[6];
  const float* bk = (const float*)d_in[7];
  const float* Wv = (const float*)d_in[8];
  const float* bv = (const float*)d_in[9];
  const float* Wf = (const float*)d_in[10];
  const float* bf = (const float*)d_in[11];

  char* ws = (char*)d_ws;
  short* Qp = (short*)(ws + 0);                              // 2 MB  bf16 [1024,1024]
  short* Kp = (short*)(ws + 2097152);                        // 32 MB bf16 [16384,1024]
  short* Vp = (short*)(ws + 35651584);                       // 32 MB bf16 [16384,1024]
  short* Vt = (short*)(ws + 69206016);                       // 32 MB bf16 [2][1024][8192]
  unsigned long long* mb = (unsigned long long*)(ws + 102760448);  // 1 MB
  float* ml = (float*)(ws + 103809024);                      // 256 KB [512][2][64]
  float* Op = (float*)(ws + 104071168);                      // 16 MB [512][64][128]
  short* summed = (short*)(ws + 120848384);                  // 2 MB  bf16 [1024,1024]

  k_pack_mask<<<32768, 256, 0, stream>>>(mask, mb);
  k_gemm_bt<true, false><<<64, 256, 0, stream>>>(inq, Wq, bq, Qp, 1024, 1024, 1024);
  k_gemm_bt<true, false><<<1024, 256, 0, stream>>>(ink, Wk, bk, Kp, 16384, 1024, 1024);
  k_gemm_bt<true, false><<<1024, 256, 0, stream>>>(inv, Wv, bv, Vp, 16384, 1024, 1024);
  k_transpose_v<<<4096, 256, 0, stream>>>(Vp, Vt);
  k_attn<<<512, 256, 0, stream>>>(Qp, Kp, Vt, mb, ml, Op);
  k_combine<<<128, 256, 0, stream>>>(ml, Op, summed);
  k_gemm_bt<false, true><<<64, 256, 0, stream>>>(summed, Wf, bf, (float*)d_out, 1024, 1024, 1024);
}

// Round 2
// 436.672 us; speedup vs baseline: 1.4599x; 1.4599x over previous
//
#include <hip/hip_runtime.h>
#include <hip/hip_bf16.h>
#include <math.h>

// B=2 QL=512 KL=8192 D=1024 H=8 HD=128
typedef __attribute__((ext_vector_type(4))) float fx4;
typedef __attribute__((ext_vector_type(4))) short sx4;
typedef __attribute__((ext_vector_type(8))) short sx8;
typedef unsigned long long u64;

#define MFMA16(a, b, c) __builtin_amdgcn_mfma_f32_16x16x16bf16_1k(a, b, c, 0, 0, 0)
#define MFMA32(a, b, c) __builtin_amdgcn_mfma_f32_16x16x32_bf16(a, b, c, 0, 0, 0)

__device__ __forceinline__ unsigned short f2bf(float f) {
  unsigned int u = __float_as_uint(f);
  return (unsigned short)((u + 0x7fffu + ((u >> 16) & 1u)) >> 16);  // RNE
}

// async global->LDS, 16B per lane; LDS dest is wave-uniform base + lane*16
typedef const __attribute__((address_space(1))) char* gc1p;
typedef __attribute__((address_space(3))) char* lc3p;
__device__ __forceinline__ void glds16(const void* g, const void* lds_uniform) {
  gc1p gp = (gc1p)(unsigned long long)(uintptr_t)g;
  lc3p lp = (lc3p)(unsigned)__builtin_amdgcn_readfirstlane((int)(unsigned)(uintptr_t)lds_uniform);
  __builtin_amdgcn_global_load_lds(gp, lp, 16, 0, 0);
}

// ---------------- f32 -> bf16 convert ----------------------------------------
__global__ __launch_bounds__(256) void k_conv(const float* __restrict__ s,
                                              short* __restrict__ d) {
  size_t i = ((size_t)blockIdx.x * 256 + threadIdx.x) * 8;
  const fx4 a = *(const fx4*)(s + i);
  const fx4 b = *(const fx4*)(s + i + 4);
  sx8 o;
  o[0] = (short)f2bf(a[0]); o[1] = (short)f2bf(a[1]);
  o[2] = (short)f2bf(a[2]); o[3] = (short)f2bf(a[3]);
  o[4] = (short)f2bf(b[0]); o[5] = (short)f2bf(b[1]);
  o[6] = (short)f2bf(b[2]); o[7] = (short)f2bf(b[3]);
  *(sx8*)(d + i) = o;
}

// 5 tensors of exactly 1M f32 each (inq, Wq, Wk, Wv, Wf)
__global__ __launch_bounds__(256) void k_conv5(const float* s0, const float* s1,
                                               const float* s2, const float* s3,
                                               const float* s4, short* d0, short* d1,
                                               short* d2, short* d3, short* d4) {
  const int seg = blockIdx.x >> 9;
  const float* s = seg == 0 ? s0 : seg == 1 ? s1 : seg == 2 ? s2 : seg == 3 ? s3 : s4;
  short* d = seg == 0 ? d0 : seg == 1 ? d1 : seg == 2 ? d2 : seg == 3 ? d3 : d4;
  size_t i = ((size_t)(blockIdx.x & 511) * 256 + threadIdx.x) * 8;
  const fx4 a = *(const fx4*)(s + i);
  const fx4 b = *(const fx4*)(s + i + 4);
  sx8 o;
  o[0] = (short)f2bf(a[0]); o[1] = (short)f2bf(a[1]);
  o[2] = (short)f2bf(a[2]); o[3] = (short)f2bf(a[3]);
  o[4] = (short)f2bf(b[0]); o[5] = (short)f2bf(b[1]);
  o[6] = (short)f2bf(b[2]); o[7] = (short)f2bf(b[3]);
  *(sx8*)(d + i) = o;
}

// ---------------- mask pack: int32 [2,512,8192] -> u64 bitmask ---------------
__global__ __launch_bounds__(256) void k_pack_mask(const int* __restrict__ mask,
                                                   u64* __restrict__ mb) {
  int g = blockIdx.x * 256 + threadIdx.x;
  u64 bal = __ballot(mask[g] != 0);
  if ((threadIdx.x & 63) == 0) mb[g >> 6] = bal;
}

// ---------------- GEMM: C[M,N] = alpha*(A[M,K] @ B[N,K]^T + bias) ------------
// bf16 A,B. 128x128 tile, BK=64, global_load_lds w16, XOR-swizzled LDS, MFMA32.
template <bool OUT_F32>
__global__ __launch_bounds__(256) void k_gemm(const short* __restrict__ A,
                                              const short* __restrict__ Bw,
                                              const float* __restrict__ bias,
                                              void* __restrict__ Cptr,
                                              int M, int N, int K, float alpha) {
  __shared__ __align__(16) short sA[8192];  // 128 rows x 64, swizzled 16B blocks
  __shared__ __align__(16) short sB[8192];
  const int t = threadIdx.x;
  const int lane = t & 63;
  const int w = t >> 6;
  const int quad = lane >> 4;
  const int l16 = lane & 15;
  const int x7 = l16 & 7;
  const int mt = M >> 7;
  const int m0 = (blockIdx.x % mt) << 7;
  const int n0 = (blockIdx.x / mt) << 7;
  const int wm = (w >> 1) << 6;
  const int wn = (w & 1) << 6;
  const fx4 fzero = {0.f, 0.f, 0.f, 0.f};
  fx4 acc[4][4];
#pragma unroll
  for (int i = 0; i < 4; i++)
#pragma unroll
    for (int j = 0; j < 4; j++) acc[i][j] = fzero;

  // staging geometry: issue j covers rows w*32+j*8 .. +7; lane: row += lane>>3,
  // slot cb = lane&7 holds global col-block (lane&7)^(row&7)
  const int srow = (lane >> 3);
  const int scb = lane & 7;

  for (int k0 = 0; k0 < K; k0 += 64) {
    __syncthreads();
#pragma unroll
    for (int j = 0; j < 4; j++) {
      const int row = w * 32 + j * 8 + srow;
      const int cb = scb ^ (row & 7);
      glds16(A + (size_t)(m0 + row) * K + k0 + cb * 8, &sA[(w * 32 + j * 8) * 64]);
      glds16(Bw + (size_t)(n0 + row) * K + k0 + cb * 8, &sB[(w * 32 + j * 8) * 64]);
    }
    __syncthreads();
#pragma unroll
    for (int kc = 0; kc < 2; kc++) {
      const int cbp = ((kc * 4 + quad) ^ x7) * 8;
      sx8 fa[4], fb[4];
#pragma unroll
      for (int i = 0; i < 4; i++) {
        fa[i] = *(const sx8*)(&sA[(wm + i * 16 + l16) * 64 + cbp]);
        fb[i] = *(const sx8*)(&sB[(wn + i * 16 + l16) * 64 + cbp]);
      }
#pragma unroll
      for (int mi = 0; mi < 4; mi++)
#pragma unroll
        for (int ni = 0; ni < 4; ni++)
          acc[mi][ni] = MFMA32(fa[mi], fb[ni], acc[mi][ni]);
    }
  }
  // epilogue: C/D layout col=lane&15, row=quad*4+reg
#pragma unroll
  for (int ni = 0; ni < 4; ni++) {
    const int col = n0 + wn + ni * 16 + l16;
    const float bval = bias[col];
#pragma unroll
    for (int mi = 0; mi < 4; mi++)
#pragma unroll
      for (int r = 0; r < 4; r++) {
        const int row = m0 + wm + mi * 16 + quad * 4 + r;
        const float v = (acc[mi][ni][r] + bval) * alpha;
        if (OUT_F32) ((float*)Cptr)[(size_t)row * N + col] = v;
        else ((unsigned short*)Cptr)[(size_t)row * N + col] = f2bf(v);
      }
  }
}

// ---------------- V transpose: Vp[16384,1024]bf16 -> Vt[2][1024][8192] -------
__global__ __launch_bounds__(256) void k_transpose_v(const short* __restrict__ Vp,
                                                     short* __restrict__ Vt) {
  __shared__ __align__(16) short tile[64 * 72];
  const int x = blockIdx.x;
  const int tm = x & 255;
  const int td = x >> 8;
  const int m0 = tm << 6;
  const int b = m0 >> 13;
  const int kl0 = m0 & 8191;
  const int d0 = td << 6;
  const int t = threadIdx.x;
  const int c = t & 7;
#pragma unroll
  for (int j = 0; j < 2; j++) {
    const int r = (t >> 3) + j * 32;
    *(sx8*)(&tile[r * 72 + c * 8]) = *(const sx8*)(Vp + (size_t)(m0 + r) * 1024 + d0 + c * 8);
  }
  __syncthreads();
#pragma unroll
  for (int j = 0; j < 2; j++) {
    const int d = (t >> 3) + j * 32;
    sx8 v;
#pragma unroll
    for (int i = 0; i < 8; i++) v[i] = tile[(c * 8 + i) * 72 + d];
    *(sx8*)(Vt + (size_t)(b * 1024 + d0 + d) * 8192 + kl0 + c * 8) = v;
  }
}

// ---------------- flash attention (S^T trick, no-max softmax) ----------------
// grid 1024: x = s + 8*(qt + 8*(h + 8*b)); WG: 64 q rows, 1024-key chunk.
// S^T = K.Q^T: C/D layout (row=key, col=q) IS the PV B-operand layout.
__global__ __launch_bounds__(256, 4) void k_attn(const short* __restrict__ Qp,
                                                 const short* __restrict__ Kp,
                                                 const short* __restrict__ Vt,
                                                 const u64* __restrict__ mb,
                                                 float* __restrict__ ml,
                                                 float* __restrict__ Op) {
  __shared__ __align__(16) short sK[8192];  // 64 keys x 128 d (256B rows, swizzled)
  __shared__ __align__(16) short sV[8192];  // 128 d x 64 keys (128B rows, swizzled)
  const int x = blockIdx.x;
  const int s = x & 7;
  const int qt = (x >> 3) & 7;
  const int h = (x >> 6) & 7;
  const int b = x >> 9;
  const int t = threadIdx.x;
  const int lane = t & 63;
  const int w = t >> 6;
  const int quad = lane >> 4;
  const int l16 = lane & 15;
  const int x7 = l16 & 7;
  const int q0 = qt << 6;
  const fx4 fzero = {0.f, 0.f, 0.f, 0.f};

  // Q A/B-frags straight from global (q row = l16, k = quad*8+j)
  const short* qbase = Qp + (size_t)(b * 512 + q0 + w * 16 + l16) * 1024 + h * 128;
  sx8 aq[4];
#pragma unroll
  for (int kc = 0; kc < 4; kc++) aq[kc] = *(const sx8*)(qbase + kc * 32 + quad * 8);

  fx4 Ot[8];
#pragma unroll
  for (int d = 0; d < 8; d++) Ot[d] = fzero;
  float lsum = 0.f;

  const short* kbase = Kp + (size_t)(b * 8192 + s * 1024) * 1024 + h * 128;
  const short* vbase = Vt + (size_t)(b * 1024 + h * 128) * 8192 + s * 1024;
  const u64* wdp = mb + (size_t)(b * 512 + q0 + w * 16 + l16) * 128 + s * 16;
  const int srow4 = lane >> 4, scb16 = lane & 15;
  const int srow8 = lane >> 3, scb8 = lane & 7;

  for (int kt = 0; kt < 16; kt++) {
    __syncthreads();
#pragma unroll
    for (int j = 0; j < 4; j++) {  // K tile: 4 rows/issue, 16 cb per 256B row
      const int row = (w * 4 + j) * 4 + srow4;
      const int cb = scb16 ^ (row & 7);
      glds16(kbase + (size_t)(kt * 64 + row) * 1024 + cb * 8, &sK[(w * 4 + j) * 512]);
    }
#pragma unroll
    for (int j = 0; j < 4; j++) {  // V^T tile: 8 rows/issue, 8 cb per 128B row
      const int row = (w * 4 + j) * 8 + srow8;
      const int cb = scb8 ^ (row & 7);
      glds16(vbase + (size_t)row * 8192 + kt * 64 + cb * 8, &sV[(w * 4 + j) * 512]);
    }
    const u64 wd = wdp[kt];
    __syncthreads();
    const unsigned lo = (unsigned)wd, hi = (unsigned)(wd >> 32);
    sx4 pk[4];
#pragma unroll
    for (int nt = 0; nt < 4; nt++) {
      fx4 a = fzero;
#pragma unroll
      for (int kc = 0; kc < 4; kc++) {
        const sx8 kf = *(const sx8*)(&sK[(nt * 16 + l16) * 128 + ((kc * 4 + quad) ^ x7) * 8]);
        a = MFMA32(kf, aq[kc], a);  // S^T: row=key, col=q
      }
      const unsigned bits = (nt & 2) ? hi : lo;
      const int sh = (nt & 1) * 16 + quad * 4;
      sx4 pko;
#pragma unroll
      for (int r = 0; r < 4; r++) {
        const float e = exp2f(a[r]);  // scale*log2e folded into Qp
        const float p = ((bits >> (sh + r)) & 1u) ? e : 0.f;
        lsum += p;
        pko[r] = (short)f2bf(p);
      }
      pk[nt] = pko;
    }
#pragma unroll
    for (int dt = 0; dt < 8; dt++) {
      fx4 o = Ot[dt];
#pragma unroll
      for (int nt = 0; nt < 4; nt++) {
        const int cb = (2 * nt + (quad >> 1)) ^ x7;
        const sx4 vf = *(const sx4*)(&sV[(dt * 16 + l16) * 64 + cb * 8 + (quad & 1) * 4]);
        o = MFMA16(vf, pk[nt], o);  // O^T: row=d, col=q
      }
      Ot[dt] = o;
    }
  }
  lsum += __shfl_xor(lsum, 16, 64);
  lsum += __shfl_xor(lsum, 32, 64);
  if (lane < 16) ml[(size_t)x * 64 + w * 16 + l16] = lsum;
  float* ob = Op + (size_t)x * 8192 + (w * 16 + l16) * 128 + quad * 4;
#pragma unroll
  for (int dt = 0; dt < 8; dt++) *(fx4*)(ob + dt * 16) = Ot[dt];
}

// ---------------- combine 8 KL-split partials -> summed bf16 -----------------
__global__ __launch_bounds__(256) void k_combine(const float* __restrict__ ml,
                                                 const float* __restrict__ Op,
                                                 short* __restrict__ summed) {
  const int xc = blockIdx.x;  // qt + 8*h + 64*b
  const int qt = xc & 7;
  const int h = (xc >> 3) & 7;
  const int b = xc >> 6;
  const int t = threadIdx.x;
  const int row = t >> 2;
  const int dg = (t & 3) * 32;
  float L = 0.f;
#pragma unroll
  for (int s = 0; s < 8; s++) L += ml[(size_t)(xc * 8 + s) * 64 + row];
  float o[32];
#pragma unroll
  for (int i = 0; i < 32; i++) o[i] = 0.f;
  if (L != 0.f) {
#pragma unroll
    for (int s = 0; s < 8; s++) {
      const float* src = Op + (size_t)(xc * 8 + s) * 8192 + row * 128 + dg;
#pragma unroll
      for (int i = 0; i < 8; i++) {
        const fx4 v = *(const fx4*)(src + i * 4);
        o[i * 4 + 0] += v[0]; o[i * 4 + 1] += v[1];
        o[i * 4 + 2] += v[2]; o[i * 4 + 3] += v[3];
      }
    }
    const float inv = 1.f / L;
#pragma unroll
    for (int i = 0; i < 32; i++) o[i] *= inv;
  }
  short* dst = summed + (size_t)(b * 512 + qt * 64 + row) * 1024 + h * 128 + dg;
#pragma unroll
  for (int i = 0; i < 4; i++) {
    sx8 pkv;
#pragma unroll
    for (int j = 0; j < 8; j++) pkv[j] = (short)f2bf(o[i * 8 + j]);
    *(sx8*)(dst + i * 8) = pkv;
  }
}

// ---------------- host ------------------------------------------------------
extern "C" void kernel_launch(void* const* d_in, const int* in_sizes, int n_in,
                              void* d_out, int out_size, void* d_ws, size_t ws_size,
                              hipStream_t stream) {
  (void)in_sizes; (void)n_in; (void)out_size; (void)ws_size;
  const float* inq = (const float*)d_in[0];
  const float* ink = (const float*)d_in[1];
  const float* inv = (const float*)d_in[2];
  const int* mask = (const int*)d_in[3];
  const float* Wq = (const float*)d_in[4];
  const float* bq = (const float*)d_in[5];
  const float* Wk = (const float*)d_in[6];
  const float* bk = (const float*)d_in[7];
  const float* Wv = (const float*)d_in[8];
  const float* bv = (const float*)d_in[9];
  const float* Wf = (const float*)d_in[10];
  const float* bf = (const float*)d_in[11];

  char* ws = (char*)d_ws;
  // 3 big 33.5MB slots with liveness aliasing + small region: total ~111 MB
  short* S1 = (short*)(ws + 0);           // ck -> cv -> Vt
  short* S2 = (short*)(ws + 33554432);    // Kp
  short* S3 = (short*)(ws + 67108864);    // Vp -> Op
  short* cq = (short*)(ws + 100663296);
  short* cwq = (short*)(ws + 102760448);
  short* cwk = (short*)(ws + 104857600);
  short* cwv = (short*)(ws + 106954752);
  short* cwf = (short*)(ws + 109051904);
  short* Qp = (short*)(ws + 111149056);
  short* summed = (short*)(ws + 113246208);
  u64* mb = (u64*)(ws + 115343360);
  float* ml = (float*)(ws + 116391936);

  const float alpha_q = 0.12751757f;  // (1/sqrt(128)) * log2(e)

  k_conv5<<<2560, 256, 0, stream>>>(inq, Wq, Wk, Wv, Wf, cq, cwq, cwk, cwv, cwf);
  k_pack_mask<<<32768, 256, 0, stream>>>(mask, mb);
  k_conv<<<8192, 256, 0, stream>>>(ink, S1);                                   // ck
  k_gemm<false><<<1024, 256, 0, stream>>>(S1, cwk, bk, S2, 16384, 1024, 1024, 1.f);  // Kp
  k_conv<<<8192, 256, 0, stream>>>(inv, S1);                                   // cv
  k_gemm<false><<<1024, 256, 0, stream>>>(S1, cwv, bv, S3, 16384, 1024, 1024, 1.f);  // Vp
  k_gemm<false><<<64, 256, 0, stream>>>(cq, cwq, bq, Qp, 1024, 1024, 1024, alpha_q);
  k_transpose_v<<<4096, 256, 0, stream>>>(S3, S1);                             // Vp -> Vt
  k_attn<<<1024, 256, 0, stream>>>(Qp, S2, S1, mb, ml, (float*)S3);            // -> ml, Op
  k_combine<<<128, 256, 0, stream>>>(ml, (const float*)S3, summed);
  k_gemm<true><<<64, 256, 0, stream>>>(summed, cwf, bf, (float*)d_out, 1024, 1024, 1024, 1.f);
}

// Round 3
// 428.139 us; speedup vs baseline: 1.4890x; 1.0199x over previous
//
#include <hip/hip_runtime.h>
#include <hip/hip_bf16.h>
#include <math.h>

// B=2 QL=512 KL=8192 D=1024 H=8 HD=128
typedef __attribute__((ext_vector_type(4))) float fx4;
typedef __attribute__((ext_vector_type(4))) short sx4;
typedef __attribute__((ext_vector_type(8))) short sx8;
typedef unsigned long long u64;

#define MFMA16(a, b, c) __builtin_amdgcn_mfma_f32_16x16x16bf16_1k(a, b, c, 0, 0, 0)
#define MFMA32(a, b, c) __builtin_amdgcn_mfma_f32_16x16x32_bf16(a, b, c, 0, 0, 0)

__device__ __forceinline__ unsigned short f2bf(float f) {
  unsigned int u = __float_as_uint(f);
  return (unsigned short)((u + 0x7fffu + ((u >> 16) & 1u)) >> 16);  // RNE
}

// async global->LDS, 16B per lane; LDS dest is wave-uniform base + lane*16
typedef const __attribute__((address_space(1))) char* gc1p;
typedef __attribute__((address_space(3))) char* lc3p;
__device__ __forceinline__ void glds16(const void* g, const void* lds_uniform) {
  gc1p gp = (gc1p)(unsigned long long)(uintptr_t)g;
  lc3p lp = (lc3p)(unsigned)__builtin_amdgcn_readfirstlane((int)(unsigned)(uintptr_t)lds_uniform);
  __builtin_amdgcn_global_load_lds(gp, lp, 16, 0, 0);
}

// ---------------- f32 -> bf16 convert (inv) ----------------------------------
__global__ __launch_bounds__(256) void k_conv(const float* __restrict__ s,
                                              short* __restrict__ d) {
  size_t i = ((size_t)blockIdx.x * 256 + threadIdx.x) * 8;
  const fx4 a = *(const fx4*)(s + i);
  const fx4 b = *(const fx4*)(s + i + 4);
  sx8 o;
  o[0] = (short)f2bf(a[0]); o[1] = (short)f2bf(a[1]);
  o[2] = (short)f2bf(a[2]); o[3] = (short)f2bf(a[3]);
  o[4] = (short)f2bf(b[0]); o[5] = (short)f2bf(b[1]);
  o[6] = (short)f2bf(b[2]); o[7] = (short)f2bf(b[3]);
  *(sx8*)(d + i) = o;
}

// ---------------- fused convert: ink (16.8M) + inq/Wq/Wk/Wv/Wf (1M each) -----
__global__ __launch_bounds__(256) void k_conv_a(const float* ink, const float* inq,
                                                const float* Wq, const float* Wk,
                                                const float* Wv, const float* Wf,
                                                short* ck, short* cq, short* cwq,
                                                short* cwk, short* cwv, short* cwf) {
  int bx = blockIdx.x;
  const float* s;
  short* d;
  size_t i;
  if (bx < 8192) {
    s = ink; d = ck; i = (size_t)bx * 2048;
  } else {
    const int r = bx - 8192;
    const int seg = r >> 9;
    s = seg == 0 ? inq : seg == 1 ? Wq : seg == 2 ? Wk : seg == 3 ? Wv : Wf;
    d = seg == 0 ? cq : seg == 1 ? cwq : seg == 2 ? cwk : seg == 3 ? cwv : cwf;
    i = (size_t)(r & 511) * 2048;
  }
  i += (size_t)threadIdx.x * 8;
  const fx4 a = *(const fx4*)(s + i);
  const fx4 b = *(const fx4*)(s + i + 4);
  sx8 o;
  o[0] = (short)f2bf(a[0]); o[1] = (short)f2bf(a[1]);
  o[2] = (short)f2bf(a[2]); o[3] = (short)f2bf(a[3]);
  o[4] = (short)f2bf(b[0]); o[5] = (short)f2bf(b[1]);
  o[6] = (short)f2bf(b[2]); o[7] = (short)f2bf(b[3]);
  *(sx8*)(d + i) = o;
}

// ---------------- mask pack: int32 [2,512,8192] -> u64 bitmask ---------------
__global__ __launch_bounds__(256) void k_pack_mask(const int* __restrict__ mask,
                                                   u64* __restrict__ mb) {
  int g = blockIdx.x * 256 + threadIdx.x;
  u64 bal = __ballot(mask[g] != 0);
  if ((threadIdx.x & 63) == 0) mb[g >> 6] = bal;
}

// ---------------- GEMM: C = alpha*(A[M,K] @ B[N,K]^T + bias) -----------------
// MODE 0: bf16 row-major C.  MODE 1: f32 row-major C.
// MODE 2: bf16 V^T output Vt[b][d][kl] with 8B-half swap when (d&8).
// n-tile fastest in blockIdx => consecutive blocks share the A strip (L2/L3),
// B (<=2MB) stays L2-resident.
template <int MODE>
__global__ __launch_bounds__(256) void k_gemm(const short* __restrict__ A,
                                              const short* __restrict__ Bw,
                                              const float* __restrict__ bias,
                                              void* __restrict__ Cptr,
                                              int M, int N, int K, float alpha) {
  __shared__ __align__(16) short sA[8192];  // 128 rows x 64, swizzled 16B blocks
  __shared__ __align__(16) short sB[8192];
  const int t = threadIdx.x;
  const int lane = t & 63;
  const int w = t >> 6;
  const int quad = lane >> 4;
  const int l16 = lane & 15;
  const int x7 = l16 & 7;
  const int ntile = N >> 7;
  const int n0 = (blockIdx.x % ntile) << 7;
  const int m0 = (blockIdx.x / ntile) << 7;
  const int wm = (w >> 1) << 6;
  const int wn = (w & 1) << 6;
  const fx4 fzero = {0.f, 0.f, 0.f, 0.f};
  fx4 acc[4][4];
#pragma unroll
  for (int i = 0; i < 4; i++)
#pragma unroll
    for (int j = 0; j < 4; j++) acc[i][j] = fzero;

  const int srow = (lane >> 3);
  const int scb = lane & 7;

  for (int k0 = 0; k0 < K; k0 += 64) {
    __syncthreads();
#pragma unroll
    for (int j = 0; j < 4; j++) {
      const int row = w * 32 + j * 8 + srow;
      const int cb = scb ^ (row & 7);
      glds16(A + (size_t)(m0 + row) * K + k0 + cb * 8, &sA[(w * 32 + j * 8) * 64]);
      glds16(Bw + (size_t)(n0 + row) * K + k0 + cb * 8, &sB[(w * 32 + j * 8) * 64]);
    }
    __syncthreads();
#pragma unroll
    for (int kc = 0; kc < 2; kc++) {
      const int cbp = ((kc * 4 + quad) ^ x7) * 8;
      sx8 fa[4], fb[4];
#pragma unroll
      for (int i = 0; i < 4; i++) {
        fa[i] = *(const sx8*)(&sA[(wm + i * 16 + l16) * 64 + cbp]);
        fb[i] = *(const sx8*)(&sB[(wn + i * 16 + l16) * 64 + cbp]);
      }
#pragma unroll
      for (int mi = 0; mi < 4; mi++)
#pragma unroll
        for (int ni = 0; ni < 4; ni++)
          acc[mi][ni] = MFMA32(fa[mi], fb[ni], acc[mi][ni]);
    }
  }
  // epilogue: C/D layout col=lane&15, row=quad*4+reg
#pragma unroll
  for (int ni = 0; ni < 4; ni++) {
    const int col = n0 + wn + ni * 16 + l16;
    const float bval = bias[col];
    if (MODE == 2) {
#pragma unroll
      for (int mi = 0; mi < 4; mi++) {
        const int rowb = m0 + wm + mi * 16 + quad * 4;
        const int bb = rowb >> 13;
        const int kl = (rowb & 8191) ^ ((col & 8) ? 4 : 0);
        sx4 pkv;
#pragma unroll
        for (int r = 0; r < 4; r++) pkv[r] = (short)f2bf(acc[mi][ni][r] + bval);
        *(sx4*)((unsigned short*)Cptr + ((size_t)bb * 1024 + col) * 8192 + kl) = pkv;
      }
    } else {
#pragma unroll
      for (int mi = 0; mi < 4; mi++)
#pragma unroll
        for (int r = 0; r < 4; r++) {
          const int row = m0 + wm + mi * 16 + quad * 4 + r;
          const float v = (acc[mi][ni][r] + bval) * alpha;
          if (MODE == 1) ((float*)Cptr)[(size_t)row * N + col] = v;
          else ((unsigned short*)Cptr)[(size_t)row * N + col] = f2bf(v);
        }
    }
  }
}

// ---------------- flash attention (S^T trick, no-max softmax) ----------------
// grid 1024: x = s + 8*(qt + 8*(h + 8*b)); WG: 64 q rows, 1024-key chunk.
__global__ __launch_bounds__(256, 4) void k_attn(const short* __restrict__ Qp,
                                                 const short* __restrict__ Kp,
                                                 const short* __restrict__ Vt,
                                                 const u64* __restrict__ mb,
                                                 float* __restrict__ ml,
                                                 float* __restrict__ Op) {
  __shared__ __align__(16) short sK[8192];  // 64 keys x 128 d (256B rows, swizzled)
  __shared__ __align__(16) short sV[8192];  // 128 d x 64 keys (128B rows, swizzled)
  const int x = blockIdx.x;
  const int s = x & 7;
  const int qt = (x >> 3) & 7;
  const int h = (x >> 6) & 7;
  const int b = x >> 9;
  const int t = threadIdx.x;
  const int lane = t & 63;
  const int w = t >> 6;
  const int quad = lane >> 4;
  const int l16 = lane & 15;
  const int x7 = l16 & 7;
  const int q0 = qt << 6;
  const fx4 fzero = {0.f, 0.f, 0.f, 0.f};

  const short* qbase = Qp + (size_t)(b * 512 + q0 + w * 16 + l16) * 1024 + h * 128;
  sx8 aq[4];
#pragma unroll
  for (int kc = 0; kc < 4; kc++) aq[kc] = *(const sx8*)(qbase + kc * 32 + quad * 8);

  fx4 Ot[8];
#pragma unroll
  for (int d = 0; d < 8; d++) Ot[d] = fzero;
  float lsum = 0.f;

  const short* kbase = Kp + (size_t)(b * 8192 + s * 1024) * 1024 + h * 128;
  const short* vbase = Vt + (size_t)(b * 1024 + h * 128) * 8192 + s * 1024;
  const u64* wdp = mb + (size_t)(b * 512 + q0 + w * 16 + l16) * 128 + s * 16;
  const int srow4 = lane >> 4, scb16 = lane & 15;
  const int srow8 = lane >> 3, scb8 = lane & 7;
  const int h4 = ((quad & 1) ^ ((l16 >> 3) & 1)) * 4;  // 8B-half parity (bank spread)

  for (int kt = 0; kt < 16; kt++) {
    __syncthreads();
#pragma unroll
    for (int j = 0; j < 4; j++) {  // K tile: 4 rows/issue
      const int row = (w * 4 + j) * 4 + srow4;
      const int cb = scb16 ^ (row & 7);
      glds16(kbase + (size_t)(kt * 64 + row) * 1024 + cb * 8, &sK[(w * 4 + j) * 512]);
    }
#pragma unroll
    for (int j = 0; j < 4; j++) {  // V^T tile: 8 rows/issue
      const int row = (w * 4 + j) * 8 + srow8;
      const int cb = scb8 ^ (row & 7);
      glds16(vbase + (size_t)row * 8192 + kt * 64 + cb * 8, &sV[(w * 4 + j) * 512]);
    }
    const u64 wd = wdp[kt];
    __syncthreads();
    const unsigned lo = (unsigned)wd, hi = (unsigned)(wd >> 32);
    sx4 pk[4];
#pragma unroll
    for (int nt = 0; nt < 4; nt++) {
      fx4 a = fzero;
#pragma unroll
      for (int kc = 0; kc < 4; kc++) {
        const sx8 kf = *(const sx8*)(&sK[(nt * 16 + l16) * 128 + ((kc * 4 + quad) ^ x7) * 8]);
        a = MFMA32(kf, aq[kc], a);  // S^T: row=key, col=q
      }
      const unsigned bits = (nt & 2) ? hi : lo;
      const int sh = (nt & 1) * 16 + quad * 4;
      float pv[4];
#pragma unroll
      for (int r = 0; r < 4; r++) {
        const float e = __builtin_amdgcn_exp2f(a[r]);  // scale*log2e folded into Qp
        pv[r] = ((bits >> (sh + r)) & 1u) ? e : 0.f;
        lsum += pv[r];
      }
      sx4 pko;
      ((unsigned*)&pko)[0] = __builtin_amdgcn_perm(
          __float_as_uint(pv[1]) + 0x8000u, __float_as_uint(pv[0]) + 0x8000u, 0x07060302u);
      ((unsigned*)&pko)[1] = __builtin_amdgcn_perm(
          __float_as_uint(pv[3]) + 0x8000u, __float_as_uint(pv[2]) + 0x8000u, 0x07060302u);
      pk[nt] = pko;
    }
#pragma unroll
    for (int dt = 0; dt < 8; dt++) {
      fx4 o = Ot[dt];
#pragma unroll
      for (int nt = 0; nt < 4; nt++) {
        const int cb = (2 * nt + (quad >> 1)) ^ x7;
        const sx4 vf = *(const sx4*)(&sV[(dt * 16 + l16) * 64 + cb * 8 + h4]);
        o = MFMA16(vf, pk[nt], o);  // O^T: row=d, col=q
      }
      Ot[dt] = o;
    }
  }
  lsum += __shfl_xor(lsum, 16, 64);
  lsum += __shfl_xor(lsum, 32, 64);
  if (lane < 16) ml[(size_t)x * 64 + w * 16 + l16] = lsum;
  float* ob = Op + (size_t)x * 8192 + (w * 16 + l16) * 128 + quad * 4;
#pragma unroll
  for (int dt = 0; dt < 8; dt++) *(fx4*)(ob + dt * 16) = Ot[dt];
}

// ---------------- combine 8 KL-split partials -> summed bf16 -----------------
__global__ __launch_bounds__(256) void k_combine(const float* __restrict__ ml,
                                                 const float* __restrict__ Op,
                                                 short* __restrict__ summed) {
  const int xc = blockIdx.x;  // qt + 8*h + 64*b
  const int qt = xc & 7;
  const int h = (xc >> 3) & 7;
  const int b = xc >> 6;
  const int t = threadIdx.x;
  const int row = t >> 2;
  const int dg = (t & 3) * 32;
  float L = 0.f;
#pragma unroll
  for (int s = 0; s < 8; s++) L += ml[(size_t)(xc * 8 + s) * 64 + row];
  float o[32];
#pragma unroll
  for (int i = 0; i < 32; i++) o[i] = 0.f;
  if (L != 0.f) {
#pragma unroll
    for (int s = 0; s < 8; s++) {
      const float* src = Op + (size_t)(xc * 8 + s) * 8192 + row * 128 + dg;
#pragma unroll
      for (int i = 0; i < 8; i++) {
        const fx4 v = *(const fx4*)(src + i * 4);
        o[i * 4 + 0] += v[0]; o[i * 4 + 1] += v[1];
        o[i * 4 + 2] += v[2]; o[i * 4 + 3] += v[3];
      }
    }
    const float inv = 1.f / L;
#pragma unroll
    for (int i = 0; i < 32; i++) o[i] *= inv;
  }
  short* dst = summed + (size_t)(b * 512 + qt * 64 + row) * 1024 + h * 128 + dg;
#pragma unroll
  for (int i = 0; i < 4; i++) {
    sx8 pkv;
#pragma unroll
    for (int j = 0; j < 8; j++) pkv[j] = (short)f2bf(o[i * 8 + j]);
    *(sx8*)(dst + i * 8) = pkv;
  }
}

// ---------------- host ------------------------------------------------------
extern "C" void kernel_launch(void* const* d_in, const int* in_sizes, int n_in,
                              void* d_out, int out_size, void* d_ws, size_t ws_size,
                              hipStream_t stream) {
  (void)in_sizes; (void)n_in; (void)out_size; (void)ws_size;
  const float* inq = (const float*)d_in[0];
  const float* ink = (const float*)d_in[1];
  const float* inv = (const float*)d_in[2];
  const int* mask = (const int*)d_in[3];
  const float* Wq = (const float*)d_in[4];
  const float* bq = (const float*)d_in[5];
  const float* Wk = (const float*)d_in[6];
  const float* bk = (const float*)d_in[7];
  const float* Wv = (const float*)d_in[8];
  const float* bv = (const float*)d_in[9];
  const float* Wf = (const float*)d_in[10];
  const float* bf = (const float*)d_in[11];

  char* ws = (char*)d_ws;
  short* S1 = (short*)(ws + 0);           // ck -> cv -> Op
  short* S2 = (short*)(ws + 33554432);    // Kp
  short* S3 = (short*)(ws + 67108864);    // Vt
  short* cq = (short*)(ws + 100663296);
  short* cwq = (short*)(ws + 102760448);
  short* cwk = (short*)(ws + 104857600);
  short* cwv = (short*)(ws + 106954752);
  short* cwf = (short*)(ws + 109051904);
  short* Qp = (short*)(ws + 111149056);
  short* summed = (short*)(ws + 113246208);
  u64* mb = (u64*)(ws + 115343360);
  float* ml = (float*)(ws + 116391936);

  const float alpha_q = 0.12751757f;  // (1/sqrt(128)) * log2(e)

  k_conv_a<<<10752, 256, 0, stream>>>(ink, inq, Wq, Wk, Wv, Wf, S1, cq, cwq, cwk, cwv, cwf);
  k_pack_mask<<<32768, 256, 0, stream>>>(mask, mb);
  k_gemm<0><<<1024, 256, 0, stream>>>(S1, cwk, bk, S2, 16384, 1024, 1024, 1.f);   // Kp
  k_conv<<<8192, 256, 0, stream>>>(inv, S1);                                      // cv
  k_gemm<2><<<1024, 256, 0, stream>>>(S1, cwv, bv, S3, 16384, 1024, 1024, 1.f);   // Vt (fused T)
  k_gemm<0><<<64, 256, 0, stream>>>(cq, cwq, bq, Qp, 1024, 1024, 1024, alpha_q);
  k_attn<<<1024, 256, 0, stream>>>(Qp, S2, S3, mb, ml, (float*)S1);               // -> ml, Op
  k_combine<<<128, 256, 0, stream>>>(ml, (const float*)S1, summed);
  k_gemm<1><<<64, 256, 0, stream>>>(summed, cwf, bf, (float*)d_out, 1024, 1024, 1024, 1.f);
}